// Round 4
// baseline (400.429 us; speedup 1.0000x reference)
//
#include <hip/hip_runtime.h>

#define B_ 4
#define T_ 2048
#define C_ 32
#define H_ 4
#define DQK 416
#define DV 512
#define QSCALE 0.049029033784546f   // 1/sqrt(416)
// kf fragment layout: [bh][kt 64][sf 26][hi 2][key 32][8]  (26 = hf*13 + s)
#define KF_BH 851968

typedef __attribute__((ext_vector_type(8))) short short8;
typedef __attribute__((ext_vector_type(4))) short short4_;
typedef __attribute__((ext_vector_type(4))) float float4_;
typedef __attribute__((ext_vector_type(16))) float f32x16;

// packed nibble tables (blade j -> value), LSB nibble = j0
#define GRADE_PK 0x4333322222211110ULL
#define E0B_PK   0x8077700066600050ULL
#define SRC_PK   0xE0A9800043200000ULL
#define IPOS_PK  0x0700065400032100ULL
#define E0MASK   0xB8E2
#define INVMASK  0x471D
#define QKMASK   0x7F1D
#define BL_PK    0xEAFD98CB43762051ULL

__device__ __forceinline__ float bf2f(unsigned short u){
  union{unsigned int i; float f;} v; v.i = ((unsigned int)u) << 16; return v.f;
}
__device__ __forceinline__ unsigned short f2bf(float f){
  union{float f; unsigned int i;} v; v.f = f;
  unsigned int x = v.i;
  unsigned int r = x + 0x7FFFu + ((x >> 16) & 1u);
  return (unsigned short)(r >> 16);
}

// ---------------- k0: weight prep ----------------
__global__ void k0_prep(const float* __restrict__ w_qkv, const float* __restrict__ w_out,
                        const float* __restrict__ lnw, const float* __restrict__ mix_ipa,
                        const float* __restrict__ mix_daa,
                        unsigned short* __restrict__ wqb, unsigned short* __restrict__ wob,
                        float* __restrict__ wI, float* __restrict__ wD){
  int idx = blockIdx.x * 256 + threadIdx.x;
  if (idx < 9*384*32){
    int i = idx & 31;
    int rest = idx >> 5;
    int o = rest % 384;
    int bb = rest / 384;
    wqb[idx] = f2bf(w_qkv[(o*32 + i)*9 + bb] * lnw[i]);
  }
  if (idx < 9*32*128){
    int i = idx & 127;
    int rest = idx >> 7;
    int o = rest & 31;
    int bb = rest >> 5;
    wob[idx] = f2bf(w_out[(o*128 + i)*9 + bb]);
  }
  if (idx < 128){
    wI[idx] = __expf(mix_ipa[idx]);
    wD[idx] = __expf(mix_daa[idx]);
  }
}

// ---------------- k1: norm + QKV equi-linear + feature build ----------------
__global__ __launch_bounds__(256) void k1_qkv(
    const float* __restrict__ x, const unsigned short* __restrict__ wqb,
    const float* __restrict__ wI, const float* __restrict__ wD,
    unsigned short* __restrict__ qf, unsigned short* __restrict__ kf,
    unsigned short* __restrict__ vt){
  extern __shared__ char smem[];
  unsigned short* xJ = (unsigned short*)smem;
  float* invr = (float*)(smem + 20480);
  float* red  = (float*)(smem + 20544);
  unsigned short* ostage = (unsigned short*)(smem + 21056);
  float* pstash = (float*)(smem + 86592);

  int tid = threadIdx.x;
  int tile = blockIdx.x;
  int b = tile >> 7;
  int t0 = (tile & 127) << 4;

  const float* xt = x + ((size_t)(b*T_ + t0)) * 512;
  #pragma unroll
  for (int pass = 0; pass < 8; ++pass){
    int g = tid + pass*256;
    int t = g >> 7, r = g & 127;
    int ci = r >> 2, j4 = (r & 3) << 2;
    float4_ v = *(const float4_*)(xt + (size_t)t*512 + ci*16 + j4);
    #pragma unroll
    for (int d = 0; d < 4; ++d){
      xJ[((j4 + d)*16 + t)*40 + ci] = f2bf(v[d]);
    }
  }
  __syncthreads();
  if (tid < 128){
    int t = tid >> 3, p = tid & 7;
    int j = (int)((0xEA984320u >> (p*4)) & 15u);
    float s = 0.f;
    #pragma unroll
    for (int i = 0; i < 32; ++i){
      float v = bf2f(xJ[(j*16 + t)*40 + i]);
      s += v*v;
    }
    red[t*8 + p] = s;
  }
  __syncthreads();
  if (tid < 16){
    float s = 0.f;
    #pragma unroll
    for (int p = 0; p < 8; ++p) s += red[tid*8 + p];
    invr[tid] = rsqrtf(s * (1.0f/32.0f) + 1e-5f);
  }
  __syncthreads();

  int wv = tid >> 6, lane = tid & 63, lm = lane & 15, kg = lane >> 4;
  unsigned short* ost = ostage + wv * 8192;
  float* pst = pstash + wv * 1536;
  int h = wv;
  int bh = b * H_ + h;

  for (int s = 0; s < 3; ++s){
    int c12 = s*4 + h;
    #pragma unroll
    for (int j = 0; j < 16; ++j){
      if (s < 2 && !((QKMASK >> j) & 1)) continue;
      int g  = (int)((GRADE_PK >> (j*4)) & 15);
      bool e0 = (E0MASK >> j) & 1;
      int eb = (int)((E0B_PK >> (j*4)) & 15);
      int sj = (int)((SRC_PK >> (j*4)) & 15);
      #pragma unroll
      for (int nt = 0; nt < 2; ++nt){
        int o = c12*32 + nt*16 + lm;
        float4_ acc = {0.f, 0.f, 0.f, 0.f};
        short8 a0 = *(const short8*)&xJ[(j*16 + lm)*40 + kg*8];
        short8 b0 = *(const short8*)&wqb[((size_t)(g*384 + o))*32 + kg*8];
        acc = __builtin_amdgcn_mfma_f32_16x16x32_bf16(a0, b0, acc, 0, 0, 0);
        if (e0){
          short8 a1 = *(const short8*)&xJ[(sj*16 + lm)*40 + kg*8];
          short8 b1 = *(const short8*)&wqb[((size_t)(eb*384 + o))*32 + kg*8];
          acc = __builtin_amdgcn_mfma_f32_16x16x32_bf16(a1, b1, acc, 0, 0, 0);
        }
        int c = nt*16 + lm;
        #pragma unroll
        for (int r = 0; r < 4; ++r){
          int t = kg*4 + r;
          float val = acc[r] * invr[t];
          if (s == 2){
            ost[t*512 + c*16 + j] = f2bf(val);
          } else if ((INVMASK >> j) & 1){
            int p = (int)((IPOS_PK >> (j*4)) & 15);
            float f = (s == 0) ? val * wI[h*32 + c] * QSCALE : val;
            ost[t*512 + c*8 + p] = f2bf(f);
          } else {
            int d = j - 11;
            float f = (s == 0) ? val * (2.0f * QSCALE) * wD[h*32 + c] : val;
            ost[t*512 + 256 + c*5 + d] = f2bf(f);
            pst[(t*32 + c)*3 + d] = val;
          }
        }
      }
    }
    if (s < 2){
      #pragma unroll
      for (int q8 = 0; q8 < 8; ++q8){
        int task = lane + q8*64;
        int t = task >> 5, c = task & 31;
        float p0 = pst[(t*32 + c)*3 + 0];
        float p1 = pst[(t*32 + c)*3 + 1];
        float p2 = pst[(t*32 + c)*3 + 2];
        float ps = p0*p0 + p1*p1 + p2*p2;
        if (s == 0){
          float wd = wD[h*32 + c] * QSCALE;
          ost[t*512 + 256 + c*5 + 3] = f2bf(-ps * wd);
          ost[t*512 + 256 + c*5 + 4] = f2bf(-wd);
        } else {
          ost[t*512 + 256 + c*5 + 3] = f2bf(1.0f);
          ost[t*512 + 256 + c*5 + 4] = f2bf(ps);
        }
      }
      if (s == 0){
        unsigned short* dst = qf + ((size_t)bh*T_ + t0) * DQK;
        for (int ch = lane; ch < 832; ch += 64){
          int t = ch / 52, c8 = ch % 52;
          *(short8*)(dst + (size_t)t*DQK + c8*8) = *(const short8*)&ost[t*512 + c8*8];
        }
      } else {
        // K store in MFMA-fragment order: [kt][hf*13+s_][hi][key32][8]
        unsigned short* dst = kf + (size_t)bh * KF_BH;
        for (int ch = lane; ch < 832; ch += 64){
          int t = ch / 52, c8 = ch % 52;
          int f0 = c8 * 8;
          int hf2 = (f0 >= 208);
          int fl = f0 - hf2*208;
          int s_ = fl >> 4;
          int hi2 = (fl >> 3) & 1;
          int tt = t0 + t;
          size_t off = ((((size_t)(tt >> 5)*26 + hf2*13 + s_)*2 + hi2)*32 + (tt & 31))*8;
          *(short8*)(dst + off) = *(const short8*)&ost[t*512 + c8*8];
        }
      }
    } else {
      int vtile = t0 >> 5, col0 = t0 & 31;
      unsigned short* vdst = vt + ((size_t)(bh*64 + vtile) * 512) * 32;
      for (int dim = lane; dim < 512; dim += 64){
        short8 v0, v1;
        #pragma unroll
        for (int t = 0; t < 8; ++t) v0[t] = (short)ost[t*512 + dim];
        #pragma unroll
        for (int t = 0; t < 8; ++t) v1[t] = (short)ost[(t + 8)*512 + dim];
        *(short8*)(vdst + (size_t)dim*32 + col0)     = v0;
        *(short8*)(vdst + (size_t)dim*32 + col0 + 8) = v1;
      }
    }
  }
}

// ---------------- k3: flash attention, 32x32 swapped-MFMA ----------------
// grid 256 = XCD-pinned [c 16][bhlo 2][xcd 8], block 512 (8 waves).
// Wave wv: chunk quad cc=wv>>1 in {c, c+16, 47-c, 63-c}, feature/V half hf=wv&1.
// K: direct-global fragment loads (kf frag layout). V: LDS double-buffered (reg-staged).
// sx: f32 score-exchange, double-buffered. ONE barrier per k-tile.
// LDS: vbuf 2x[512][40] (81920) | sx 2x 8x[32][36] f32 (73728) => 155648B
__global__ __launch_bounds__(512, 2) void k3_attn(
    const unsigned short* __restrict__ qf, const unsigned short* __restrict__ kf,
    const unsigned short* __restrict__ vt, unsigned short* __restrict__ O){
  extern __shared__ char smem[];
  unsigned short* vbuf = (unsigned short*)smem;            // 2 x 20480 shorts
  float* sx = (float*)(smem + 81920);                      // 2 x 9216 f32
  unsigned short* ostage = (unsigned short*)smem;          // epilogue alias [32][536]

  int tid = threadIdx.x, wv = tid >> 6, lane = tid & 63;
  int ql = lane & 31, hi = lane >> 5, hf = wv & 1, cc = wv >> 1;
  int blk = blockIdx.x;
  int bh = 2*(blk & 7) + ((blk >> 3) & 1);
  int c = blk >> 4;
  int chunk = (cc == 0) ? c : (cc == 1) ? c + 16 : (cc == 2) ? 47 - c : 63 - c;
  int q0 = chunk * 32;
  int nkt = 64 - c;

  const unsigned short* qfb = qf + (size_t)bh * T_ * DQK;
  const unsigned short* kfb = kf + (size_t)bh * KF_BH + (size_t)(hf*13)*512 + hi*256 + ql*8;
  const unsigned short* vtb = vt + (size_t)bh * 64 * 512 * 32;
  unsigned short* Ob = O + (size_t)bh * T_ * DV;

  // Q fragments: 13 x b128 (this wave's feature half)
  short8 qfr[13];
  {
    const unsigned short* qrow = qfb + (size_t)(q0 + ql) * DQK + hf*208 + hi*8;
    #pragma unroll
    for (int s_ = 0; s_ < 13; ++s_) qfr[s_] = *(const short8*)(qrow + s_*16);
  }

  f32x16 acc[8];
  #pragma unroll
  for (int i = 0; i < 8; ++i){
    #pragma unroll
    for (int j = 0; j < 16; ++j) acc[i][j] = 0.f;
  }
  float m = -1e30f, l = 0.f;
  f32x16 Sc;   // own-half scores for tile t (computed one iteration ahead)

  short8 vr0, vr1, vr2, vr3;
  // ---- prologue: V(0) stage, QK(0), sx(0) ----
  {
    const unsigned short* vs = vtb;
    vr0 = *(const short8*)(vs + (size_t)(0*512 + tid)*8);
    vr1 = *(const short8*)(vs + (size_t)(1*512 + tid)*8);
    vr2 = *(const short8*)(vs + (size_t)(2*512 + tid)*8);
    vr3 = *(const short8*)(vs + (size_t)(3*512 + tid)*8);
    #pragma unroll
    for (int j = 0; j < 16; ++j) Sc[j] = 0.f;
    #pragma unroll
    for (int s_ = 0; s_ < 13; ++s_){
      short8 kfrag = *(const short8*)(kfb + (size_t)s_*512);
      Sc = __builtin_amdgcn_mfma_f32_32x32x16_bf16(kfrag, qfr[s_], Sc, 0, 0, 0);
    }
    float* sxw = sx + wv*1152 + ql*36;
    #pragma unroll
    for (int g = 0; g < 4; ++g){
      float4_ w4;
      #pragma unroll
      for (int u = 0; u < 4; ++u) w4[u] = Sc[g*4 + u];
      *(float4_*)(sxw + g*8 + hi*4) = w4;
    }
    int i0 = 0*512 + tid, i1 = 1*512 + tid, i2 = 2*512 + tid, i3 = 3*512 + tid;
    *(short8*)&vbuf[(i0>>2)*40 + (i0&3)*8] = vr0;
    *(short8*)&vbuf[(i1>>2)*40 + (i1&3)*8] = vr1;
    *(short8*)&vbuf[(i2>>2)*40 + (i2&3)*8] = vr2;
    *(short8*)&vbuf[(i3>>2)*40 + (i3&3)*8] = vr3;
  }
  __syncthreads();

  for (int kt = 0; kt < nkt; ++kt){
    int cur = kt & 1, nxt = cur ^ 1;
    bool pf = (kt + 1 < nkt);
    if (pf){
      const unsigned short* vs = vtb + (size_t)(kt+1)*16384;
      vr0 = *(const short8*)(vs + (size_t)(0*512 + tid)*8);
      vr1 = *(const short8*)(vs + (size_t)(1*512 + tid)*8);
      vr2 = *(const short8*)(vs + (size_t)(2*512 + tid)*8);
      vr3 = *(const short8*)(vs + (size_t)(3*512 + tid)*8);
    }
    if (kt <= chunk){
      // merge partner's score half
      const float* sxr = sx + cur*9216 + (wv^1)*1152 + ql*36;
      float s_[16];
      #pragma unroll
      for (int g = 0; g < 4; ++g){
        float4_ q4 = *(const float4_*)(sxr + g*8 + hi*4);
        #pragma unroll
        for (int u = 0; u < 4; ++u) s_[g*4 + u] = Sc[g*4 + u] + q4[u];
      }
      // causal mask (diagonal tile)
      if (kt == chunk){
        #pragma unroll
        for (int r = 0; r < 16; ++r){
          int kr = (r & 3) + 8*(r >> 2) + 4*hi;
          if (kr > ql) s_[r] = -1e30f;
        }
      }
      // online softmax (lane-local rows; cross-half pair via xor 32)
      float pmax = s_[0];
      #pragma unroll
      for (int r = 1; r < 16; ++r) pmax = fmaxf(pmax, s_[r]);
      pmax = fmaxf(pmax, __shfl_xor(pmax, 32));
      bool keep = __all(pmax <= m + 8.0f);
      if (!keep){
        float mn = fmaxf(m, pmax);
        float al = __expf(m - mn);
        m = mn; l *= al;
        #pragma unroll
        for (int dt = 0; dt < 8; ++dt) acc[dt] *= al;
      }
      float p[16]; float rs = 0.f;
      #pragma unroll
      for (int r = 0; r < 16; ++r){ p[r] = __expf(s_[r] - m); rs += p[r]; }
      rs += __shfl_xor(rs, 32);
      l += rs;
      // QK for tile kt+1 (K direct from global, fragment layout)
      if (kt + 1 <= chunk){
        f32x16 Sn;
        #pragma unroll
        for (int j = 0; j < 16; ++j) Sn[j] = 0.f;
        const unsigned short* kb = kfb + (size_t)(kt+1)*26*512;
        __builtin_amdgcn_s_setprio(1);
        #pragma unroll
        for (int s2 = 0; s2 < 13; ++s2){
          short8 kfrag = *(const short8*)(kb + (size_t)s2*512);
          Sn = __builtin_amdgcn_mfma_f32_32x32x16_bf16(kfrag, qfr[s2], Sn, 0, 0, 0);
        }
        __builtin_amdgcn_s_setprio(0);
        float* sxw = sx + nxt*9216 + wv*1152 + ql*36;
        #pragma unroll
        for (int g = 0; g < 4; ++g){
          float4_ w4;
          #pragma unroll
          for (int u = 0; u < 4; ++u) w4[u] = Sn[g*4 + u];
          *(float4_*)(sxw + g*8 + hi*4) = w4;
        }
        Sc = Sn;
      }
      // pack P^T into B-fragments
      unsigned A0 = (unsigned)f2bf(p[0])  | ((unsigned)f2bf(p[1])  << 16);
      unsigned A1 = (unsigned)f2bf(p[2])  | ((unsigned)f2bf(p[3])  << 16);
      unsigned A2 = (unsigned)f2bf(p[4])  | ((unsigned)f2bf(p[5])  << 16);
      unsigned A3 = (unsigned)f2bf(p[6])  | ((unsigned)f2bf(p[7])  << 16);
      unsigned A4 = (unsigned)f2bf(p[8])  | ((unsigned)f2bf(p[9])  << 16);
      unsigned A5 = (unsigned)f2bf(p[10]) | ((unsigned)f2bf(p[11]) << 16);
      unsigned A6 = (unsigned)f2bf(p[12]) | ((unsigned)f2bf(p[13]) << 16);
      unsigned A7 = (unsigned)f2bf(p[14]) | ((unsigned)f2bf(p[15]) << 16);
      unsigned S0 = __shfl_xor((int)A0, 32), S2 = __shfl_xor((int)A2, 32);
      unsigned S1 = __shfl_xor((int)A1, 32), S3 = __shfl_xor((int)A3, 32);
      unsigned S4 = __shfl_xor((int)A4, 32), S6 = __shfl_xor((int)A6, 32);
      unsigned S5 = __shfl_xor((int)A5, 32), S7 = __shfl_xor((int)A7, 32);
      union { unsigned u[4]; short8 s8; } P0, P1;
      P0.u[0] = hi ? S2 : A0;  P0.u[1] = hi ? S3 : A1;
      P0.u[2] = hi ? A2 : S0;  P0.u[3] = hi ? A3 : S1;
      P1.u[0] = hi ? S6 : A4;  P1.u[1] = hi ? S7 : A5;
      P1.u[2] = hi ? A6 : S4;  P1.u[3] = hi ? A7 : S5;
      // PV: own 256-dim half from vbuf[cur]
      const unsigned short* vc = vbuf + cur*20480;
      __builtin_amdgcn_s_setprio(1);
      #pragma unroll
      for (int dt = 0; dt < 8; ++dt){
        const unsigned short* vrow = &vc[(unsigned)(hf*256 + dt*32 + ql)*40];
        short8 v0 = *(const short8*)(vrow + hi*8);
        short8 v1 = *(const short8*)(vrow + 16 + hi*8);
        acc[dt] = __builtin_amdgcn_mfma_f32_32x32x16_bf16(v0, P0.s8, acc[dt], 0, 0, 0);
        acc[dt] = __builtin_amdgcn_mfma_f32_32x32x16_bf16(v1, P1.s8, acc[dt], 0, 0, 0);
      }
      __builtin_amdgcn_s_setprio(0);
    }
    // stage V(kt+1) into the other buffer (no reader conflict: dbuf)
    if (pf){
      unsigned short* vd = vbuf + nxt*20480;
      int i0 = 0*512 + tid, i1 = 1*512 + tid, i2 = 2*512 + tid, i3 = 3*512 + tid;
      *(short8*)&vd[(i0>>2)*40 + (i0&3)*8] = vr0;
      *(short8*)&vd[(i1>>2)*40 + (i1&3)*8] = vr1;
      *(short8*)&vd[(i2>>2)*40 + (i2&3)*8] = vr2;
      *(short8*)&vd[(i3>>2)*40 + (i3&3)*8] = vr3;
    }
    __syncthreads();
  }

  // ---- epilogue: normalize, transpose via LDS, coalesced store ----
  float il = 1.0f / l;
  for (int ccs = 0; ccs < 4; ++ccs){
    int cbase = ((ccs == 0) ? c : (ccs == 1) ? c + 16 : (ccs == 2) ? 47 - c : 63 - c) * 32;
    if (cc == ccs){
      #pragma unroll
      for (int dt = 0; dt < 8; ++dt){
        #pragma unroll
        for (int g = 0; g < 4; ++g){
          int d0 = hf*256 + dt*32 + g*8 + hi*4;
          short4_ w;
          #pragma unroll
          for (int u = 0; u < 4; ++u) w[u] = (short)f2bf(acc[dt][g*4 + u] * il);
          *(short4_*)&ostage[ql*536 + d0] = w;
        }
      }
    }
    __syncthreads();
    #pragma unroll
    for (int p = 0; p < 4; ++p){
      int row = p*8 + wv;
      *(short8*)(Ob + (size_t)(cbase + row)*DV + lane*8) = *(const short8*)&ostage[row*536 + lane*8];
    }
    __syncthreads();
  }
}

// ---------------- k4: out equi-linear + residual ----------------
__global__ __launch_bounds__(256) void k4_out(
    const unsigned short* __restrict__ O, const unsigned short* __restrict__ wob,
    const float* __restrict__ x, float* __restrict__ out){
  extern __shared__ char smem[];
  unsigned short* oT = (unsigned short*)smem;
  float* fst = (float*)(smem + 69632);

  int tid = threadIdx.x, wv = tid >> 6, lane = tid & 63, lm = lane & 15, kg = lane >> 4;
  int blk = blockIdx.x;
  int b = blk >> 7, t0 = (blk & 127) << 4;

  for (int ch = tid; ch < 4096; ch += 256){
    int hh = ch >> 10, t = (ch >> 6) & 15, c8 = ch & 63;
    short8 v = *(const short8*)(O + ((size_t)(b*H_ + hh)*T_ + (t0 + t))*512 + c8*8);
    int c = c8 >> 1, j0 = (c8 & 1)*8;
    int ci = hh*32 + c;
    #pragma unroll
    for (int d = 0; d < 8; ++d)
      oT[((j0 + d)*16 + t)*136 + ci] = (unsigned short)v[d];
  }
  __syncthreads();

  #pragma unroll
  for (int bi = 0; bi < 4; ++bi){
    int j  = (int)((BL_PK >> ((wv*4 + bi)*4)) & 15);
    int g  = (int)((GRADE_PK >> (j*4)) & 15);
    bool e0 = (E0MASK >> j) & 1;
    int eb = (int)((E0B_PK >> (j*4)) & 15);
    int sj = (int)((SRC_PK >> (j*4)) & 15);
    #pragma unroll
    for (int nt = 0; nt < 2; ++nt){
      int o = nt*16 + lm;
      float4_ acc = {0.f, 0.f, 0.f, 0.f};
      #pragma unroll
      for (int ks = 0; ks < 4; ++ks){
        short8 a = *(const short8*)&oT[(j*16 + lm)*136 + ks*32 + kg*8];
        short8 bfr = *(const short8*)(wob + ((size_t)(g*32 + o))*128 + ks*32 + kg*8);
        acc = __builtin_amdgcn_mfma_f32_16x16x32_bf16(a, bfr, acc, 0, 0, 0);
      }
      if (e0){
        #pragma unroll
        for (int ks = 0; ks < 4; ++ks){
          short8 a = *(const short8*)&oT[(sj*16 + lm)*136 + ks*32 + kg*8];
          short8 bfr = *(const short8*)(wob + ((size_t)(eb*32 + o))*128 + ks*32 + kg*8);
          acc = __builtin_amdgcn_mfma_f32_16x16x32_bf16(a, bfr, acc, 0, 0, 0);
        }
      }
      #pragma unroll
      for (int r = 0; r < 4; ++r){
        int t = kg*4 + r;
        fst[t*512 + o*16 + j] = acc[r];
      }
    }
  }
  __syncthreads();
  const float* xb = x + ((size_t)(b*T_ + t0))*512;
  float* ob = out + ((size_t)(b*T_ + t0))*512;
  for (int ch = tid; ch < 2048; ch += 256){
    float4_ v  = *(const float4_*)(fst + (size_t)ch*4);
    float4_ xv = *(const float4_*)(xb + (size_t)ch*4);
    *(float4_*)(ob + (size_t)ch*4) = v + xv;
  }
}

// ---------------- launcher ----------------
extern "C" void kernel_launch(void* const* d_in, const int* in_sizes, int n_in,
                              void* d_out, int out_size, void* d_ws, size_t ws_size,
                              hipStream_t stream){
  const float* x       = (const float*)d_in[0];
  const float* lnw     = (const float*)d_in[1];
  const float* w_qkv   = (const float*)d_in[2];
  const float* w_out   = (const float*)d_in[3];
  const float* mix_ipa = (const float*)d_in[4];
  const float* mix_daa = (const float*)d_in[5];
  float* out = (float*)d_out;

  // qf 27,262,976 | kf 27,262,976 | vt 33,554,432 | O 33,554,432
  // wqb 221,184 | wob 73,728 | wI 512 | wD 512  => 121,930,752
  if (ws_size < 121930752u) return;

  char* ws = (char*)d_ws;
  unsigned short* qf  = (unsigned short*)(ws + 0);
  unsigned short* kf  = (unsigned short*)(ws + 27262976);
  unsigned short* vt  = (unsigned short*)(ws + 54525952);
  unsigned short* O   = (unsigned short*)(ws + 88080384);
  unsigned short* wqb = (unsigned short*)(ws + 121634816);
  unsigned short* wob = (unsigned short*)(ws + 121856000);
  float* wI = (float*)(ws + 121929728);
  float* wD = (float*)(ws + 121930240);

  k0_prep<<<432, 256, 0, stream>>>(w_qkv, w_out, lnw, mix_ipa, mix_daa, wqb, wob, wI, wD);
  k1_qkv<<<512, 256, 111168, stream>>>(x, wqb, wI, wD, qf, kf, vt);
  k3_attn<<<256, 512, 155648, stream>>>(qf, kf, vt, O);
  k4_out<<<512, 256, 102400, stream>>>(O, wob, x, out);
}

// Round 5
// 246.216 us; speedup vs baseline: 1.6263x; 1.6263x over previous
//
#include <hip/hip_runtime.h>

#define B_ 4
#define T_ 2048
#define C_ 32
#define H_ 4
#define DQK 416
#define DV 512
#define QSCALE 0.049029033784546f   // 1/sqrt(416)
// kf fragment layout: [bh][kt 64][sf 26][hi 2][key 32][8]
#define KF_BH 851968
#define KF_KT 13312      // shorts per kt tile (26*2*32*8)
// vt fragment layout: [bh][kt 64][dt 16][kh 2][lane 64][8]
#define VT_KT 16384      // shorts per kt tile

typedef __attribute__((ext_vector_type(8))) short short8;
typedef __attribute__((ext_vector_type(4))) short short4_;
typedef __attribute__((ext_vector_type(4))) float float4_;
typedef __attribute__((ext_vector_type(16))) float f32x16;

#define GLOBAL_AS __attribute__((address_space(1)))
#define LDS_AS __attribute__((address_space(3)))

// packed nibble tables (blade j -> value), LSB nibble = j0
#define GRADE_PK 0x4333322222211110ULL
#define E0B_PK   0x8077700066600050ULL
#define SRC_PK   0xE0A9800043200000ULL
#define IPOS_PK  0x0700065400032100ULL
#define E0MASK   0xB8E2
#define INVMASK  0x471D
#define QKMASK   0x7F1D
#define BL_PK    0xEAFD98CB43762051ULL

__device__ __forceinline__ float bf2f(unsigned short u){
  union{unsigned int i; float f;} v; v.i = ((unsigned int)u) << 16; return v.f;
}
__device__ __forceinline__ unsigned short f2bf(float f){
  union{float f; unsigned int i;} v; v.f = f;
  unsigned int x = v.i;
  unsigned int r = x + 0x7FFFu + ((x >> 16) & 1u);
  return (unsigned short)(r >> 16);
}

// ---------------- k0: weight prep ----------------
__global__ void k0_prep(const float* __restrict__ w_qkv, const float* __restrict__ w_out,
                        const float* __restrict__ lnw, const float* __restrict__ mix_ipa,
                        const float* __restrict__ mix_daa,
                        unsigned short* __restrict__ wqb, unsigned short* __restrict__ wob,
                        float* __restrict__ wI, float* __restrict__ wD){
  int idx = blockIdx.x * 256 + threadIdx.x;
  if (idx < 9*384*32){
    int i = idx & 31;
    int rest = idx >> 5;
    int o = rest % 384;
    int bb = rest / 384;
    wqb[idx] = f2bf(w_qkv[(o*32 + i)*9 + bb] * lnw[i]);
  }
  if (idx < 9*32*128){
    int i = idx & 127;
    int rest = idx >> 7;
    int o = rest & 31;
    int bb = rest >> 5;
    wob[idx] = f2bf(w_out[(o*128 + i)*9 + bb]);
  }
  if (idx < 128){
    wI[idx] = __expf(mix_ipa[idx]);
    wD[idx] = __expf(mix_daa[idx]);
  }
}

// ---------------- k1: norm + QKV equi-linear + feature build ----------------
__global__ __launch_bounds__(256) void k1_qkv(
    const float* __restrict__ x, const unsigned short* __restrict__ wqb,
    const float* __restrict__ wI, const float* __restrict__ wD,
    unsigned short* __restrict__ qf, unsigned short* __restrict__ kf,
    unsigned short* __restrict__ vt){
  extern __shared__ char smem[];
  unsigned short* xJ = (unsigned short*)smem;
  float* invr = (float*)(smem + 20480);
  float* red  = (float*)(smem + 20544);
  unsigned short* ostage = (unsigned short*)(smem + 21056);
  float* pstash = (float*)(smem + 86592);

  int tid = threadIdx.x;
  int tile = blockIdx.x;
  int b = tile >> 7;
  int t0 = (tile & 127) << 4;

  const float* xt = x + ((size_t)(b*T_ + t0)) * 512;
  #pragma unroll
  for (int pass = 0; pass < 8; ++pass){
    int g = tid + pass*256;
    int t = g >> 7, r = g & 127;
    int ci = r >> 2, j4 = (r & 3) << 2;
    float4_ v = *(const float4_*)(xt + (size_t)t*512 + ci*16 + j4);
    #pragma unroll
    for (int d = 0; d < 4; ++d){
      xJ[((j4 + d)*16 + t)*40 + ci] = f2bf(v[d]);
    }
  }
  __syncthreads();
  if (tid < 128){
    int t = tid >> 3, p = tid & 7;
    int j = (int)((0xEA984320u >> (p*4)) & 15u);
    float s = 0.f;
    #pragma unroll
    for (int i = 0; i < 32; ++i){
      float v = bf2f(xJ[(j*16 + t)*40 + i]);
      s += v*v;
    }
    red[t*8 + p] = s;
  }
  __syncthreads();
  if (tid < 16){
    float s = 0.f;
    #pragma unroll
    for (int p = 0; p < 8; ++p) s += red[tid*8 + p];
    invr[tid] = rsqrtf(s * (1.0f/32.0f) + 1e-5f);
  }
  __syncthreads();

  int wv = tid >> 6, lane = tid & 63, lm = lane & 15, kg = lane >> 4;
  unsigned short* ost = ostage + wv * 8192;
  float* pst = pstash + wv * 1536;
  int h = wv;
  int bh = b * H_ + h;

  for (int s = 0; s < 3; ++s){
    int c12 = s*4 + h;
    #pragma unroll
    for (int j = 0; j < 16; ++j){
      if (s < 2 && !((QKMASK >> j) & 1)) continue;
      int g  = (int)((GRADE_PK >> (j*4)) & 15);
      bool e0 = (E0MASK >> j) & 1;
      int eb = (int)((E0B_PK >> (j*4)) & 15);
      int sj = (int)((SRC_PK >> (j*4)) & 15);
      #pragma unroll
      for (int nt = 0; nt < 2; ++nt){
        int o = c12*32 + nt*16 + lm;
        float4_ acc = {0.f, 0.f, 0.f, 0.f};
        short8 a0 = *(const short8*)&xJ[(j*16 + lm)*40 + kg*8];
        short8 b0 = *(const short8*)&wqb[((size_t)(g*384 + o))*32 + kg*8];
        acc = __builtin_amdgcn_mfma_f32_16x16x32_bf16(a0, b0, acc, 0, 0, 0);
        if (e0){
          short8 a1 = *(const short8*)&xJ[(sj*16 + lm)*40 + kg*8];
          short8 b1 = *(const short8*)&wqb[((size_t)(eb*384 + o))*32 + kg*8];
          acc = __builtin_amdgcn_mfma_f32_16x16x32_bf16(a1, b1, acc, 0, 0, 0);
        }
        int c = nt*16 + lm;
        #pragma unroll
        for (int r = 0; r < 4; ++r){
          int t = kg*4 + r;
          float val = acc[r] * invr[t];
          if (s == 2){
            ost[t*512 + c*16 + j] = f2bf(val);
          } else if ((INVMASK >> j) & 1){
            int p = (int)((IPOS_PK >> (j*4)) & 15);
            float f = (s == 0) ? val * wI[h*32 + c] * QSCALE : val;
            ost[t*512 + c*8 + p] = f2bf(f);
          } else {
            int d = j - 11;
            float f = (s == 0) ? val * (2.0f * QSCALE) * wD[h*32 + c] : val;
            ost[t*512 + 256 + c*5 + d] = f2bf(f);
            pst[(t*32 + c)*3 + d] = val;
          }
        }
      }
    }
    if (s < 2){
      #pragma unroll
      for (int q8 = 0; q8 < 8; ++q8){
        int task = lane + q8*64;
        int t = task >> 5, c = task & 31;
        float p0 = pst[(t*32 + c)*3 + 0];
        float p1 = pst[(t*32 + c)*3 + 1];
        float p2 = pst[(t*32 + c)*3 + 2];
        float ps = p0*p0 + p1*p1 + p2*p2;
        if (s == 0){
          float wd = wD[h*32 + c] * QSCALE;
          ost[t*512 + 256 + c*5 + 3] = f2bf(-ps * wd);
          ost[t*512 + 256 + c*5 + 4] = f2bf(-wd);
        } else {
          ost[t*512 + 256 + c*5 + 3] = f2bf(1.0f);
          ost[t*512 + 256 + c*5 + 4] = f2bf(ps);
        }
      }
      if (s == 0){
        unsigned short* dst = qf + ((size_t)bh*T_ + t0) * DQK;
        for (int ch = lane; ch < 832; ch += 64){
          int t = ch / 52, c8 = ch % 52;
          *(short8*)(dst + (size_t)t*DQK + c8*8) = *(const short8*)&ost[t*512 + c8*8];
        }
      } else {
        // K store in MFMA-fragment order: [kt][sf][hi][key32][8]
        unsigned short* dst = kf + (size_t)bh * KF_BH;
        for (int ch = lane; ch < 832; ch += 64){
          int t = ch / 52, c8 = ch % 52;
          int f0 = c8 * 8;
          int hf2 = (f0 >= 208);
          int fl = f0 - hf2*208;
          int s_ = fl >> 4;
          int hi2 = (fl >> 3) & 1;
          int tt = t0 + t;
          size_t off = ((((size_t)(tt >> 5)*26 + hf2*13 + s_)*2 + hi2)*32 + (tt & 31))*8;
          *(short8*)(dst + off) = *(const short8*)&ost[t*512 + c8*8];
        }
      }
    } else {
      // V store in fragment order: [kt][dt 16][kh 2][lane 64][8]
      int kt = t0 >> 5, kh = (t0 >> 4) & 1;
      unsigned short* vdst = vt + (size_t)bh * 64 * VT_KT + (size_t)kt * VT_KT + kh * 512;
      for (int dim = lane; dim < 512; dim += 64){
        int dt = dim >> 5, qll = dim & 31;
        short8 v0, v1;
        #pragma unroll
        for (int t = 0; t < 8; ++t) v0[t] = (short)ost[t*512 + dim];
        #pragma unroll
        for (int t = 0; t < 8; ++t) v1[t] = (short)ost[(t + 8)*512 + dim];
        *(short8*)(vdst + dt*1024 + qll*8)       = v0;
        *(short8*)(vdst + dt*1024 + 256 + qll*8) = v1;
      }
    }
  }
}

// ---------------- k3: flash attention, 32x32 swapped-MFMA, 4-way feat/dim split ----------
// grid 1024 = [chunk desc 64][bhlo 2][xcd 8], block 256 (4 waves), 2 blocks/CU.
// Wave wv: QK feature quarter (sf {0-6,7-13,14-19,20-25}), PV dim quarter (wv*128..+128).
// K: global_load_lds double-buffered. V: direct-global fragment loads (issued early).
// S merged via sx LDS (4-way). 2 barriers/iter. All waves active every iter.
// LDS: kbuf 2x13312 shorts (53248B) | sx 4x[32][36] f32 (18432B) => 71680B
__device__ __forceinline__ void stageK2(const unsigned short* src, unsigned short* dst, int tid){
  const char* s = (const char*)src;
  char* d = (char*)dst;
  #pragma unroll
  for (int i = 0; i < 6; ++i)
    __builtin_amdgcn_global_load_lds((const GLOBAL_AS void*)(s + (i*256 + tid)*16),
                                     (LDS_AS void*)(d + (i*256 + tid)*16), 16, 0, 0);
  if (tid < 128)   // wave-uniform for waves 0,1
    __builtin_amdgcn_global_load_lds((const GLOBAL_AS void*)(s + (1536 + tid)*16),
                                     (LDS_AS void*)(d + (1536 + tid)*16), 16, 0, 0);
}

__global__ __launch_bounds__(256, 2) void k3_attn(
    const unsigned short* __restrict__ qf, const unsigned short* __restrict__ kf,
    const unsigned short* __restrict__ vt, unsigned short* __restrict__ O){
  extern __shared__ char smem[];
  unsigned short* kbuf = (unsigned short*)smem;          // 2 x 13312 shorts
  float* sx = (float*)(smem + 53248);                    // 4 x 32 x 36 f32
  unsigned short* ostage = (unsigned short*)smem;        // epilogue alias [32][536]

  int tid = threadIdx.x, wv = tid >> 6, lane = tid & 63;
  int ql = lane & 31, hi = lane >> 5;
  int blk = blockIdx.x;
  int bh = 2*(blk & 7) + ((blk >> 3) & 1);
  int chunk = 63 - (blk >> 4);
  int q0 = chunk * 32;

  const unsigned short* qfb = qf + (size_t)bh * T_ * DQK;
  const unsigned short* kfb = kf + (size_t)bh * KF_BH;
  const unsigned short* vtb = vt + (size_t)bh * 64 * VT_KT;
  unsigned short* Ob = O + (size_t)bh * T_ * DV;

  int FS = (wv < 2) ? wv*7 : 14 + (wv - 2)*6;     // sf base
  int FB = (wv < 2) ? wv*112 : 224 + (wv - 2)*96; // feature base

  // Q fragments (6 or 7 per wave)
  short8 qfr[7];
  {
    const unsigned short* qrow = qfb + (size_t)(q0 + ql)*DQK + FB + hi*8;
    #pragma unroll
    for (int s_ = 0; s_ < 6; ++s_) qfr[s_] = *(const short8*)(qrow + s_*16);
    if (wv < 2) qfr[6] = *(const short8*)(qrow + 96);
  }

  f32x16 acc[4];
  #pragma unroll
  for (int i = 0; i < 4; ++i){
    #pragma unroll
    for (int j = 0; j < 16; ++j) acc[i][j] = 0.f;
  }
  float m = -1e30f, l = 0.f;

  // prologue: stage K(0)
  stageK2(kfb, kbuf, tid);
  __syncthreads();

  for (int kt = 0; kt <= chunk; ++kt){
    int cur = kt & 1, nxt = cur ^ 1;
    // V fragment loads: issue early, consumed after barrier
    short8 vf[8];
    {
      const unsigned short* vk = vtb + (size_t)kt * VT_KT;
      #pragma unroll
      for (int dti = 0; dti < 4; ++dti){
        vf[dti*2]     = *(const short8*)(vk + (wv*4 + dti)*1024 + lane*8);
        vf[dti*2 + 1] = *(const short8*)(vk + (wv*4 + dti)*1024 + 512 + lane*8);
      }
    }
    // QK quarter
    f32x16 S;
    #pragma unroll
    for (int j = 0; j < 16; ++j) S[j] = 0.f;
    const unsigned short* kb = kbuf + cur*KF_KT;
    __builtin_amdgcn_s_setprio(1);
    #pragma unroll
    for (int s_ = 0; s_ < 6; ++s_){
      short8 kfrag = *(const short8*)&kb[(FS + s_)*512 + hi*256 + ql*8];
      S = __builtin_amdgcn_mfma_f32_32x32x16_bf16(kfrag, qfr[s_], S, 0, 0, 0);
    }
    if (wv < 2){
      short8 kfrag = *(const short8*)&kb[(FS + 6)*512 + hi*256 + ql*8];
      S = __builtin_amdgcn_mfma_f32_32x32x16_bf16(kfrag, qfr[6], S, 0, 0, 0);
    }
    __builtin_amdgcn_s_setprio(0);
    // write own quarter-scores
    {
      float* sxw = sx + wv*1152 + ql*36;
      #pragma unroll
      for (int g = 0; g < 4; ++g){
        float4_ w4;
        #pragma unroll
        for (int u = 0; u < 4; ++u) w4[u] = S[g*4 + u];
        *(float4_*)(sxw + g*8 + hi*4) = w4;
      }
    }
    __syncthreads();   // B1: quarters exchanged
    // merge 3 partners
    float s_[16];
    {
      int w1 = (wv + 1) & 3, w2 = (wv + 2) & 3, w3 = (wv + 3) & 3;
      #pragma unroll
      for (int g = 0; g < 4; ++g){
        float4_ a1 = *(const float4_*)(sx + w1*1152 + ql*36 + g*8 + hi*4);
        float4_ a2 = *(const float4_*)(sx + w2*1152 + ql*36 + g*8 + hi*4);
        float4_ a3 = *(const float4_*)(sx + w3*1152 + ql*36 + g*8 + hi*4);
        #pragma unroll
        for (int u = 0; u < 4; ++u) s_[g*4 + u] = S[g*4 + u] + a1[u] + a2[u] + a3[u];
      }
    }
    // stage next K (drains at B2, hidden under softmax+PV)
    if (kt < chunk) stageK2(kfb + (size_t)(kt + 1)*KF_KT, kbuf + nxt*KF_KT, tid);
    // causal mask (diagonal tile)
    if (kt == chunk){
      #pragma unroll
      for (int r = 0; r < 16; ++r){
        int kr = (r & 3) + 8*(r >> 2) + 4*hi;
        if (kr > ql) s_[r] = -1e30f;
      }
    }
    // online softmax (lane-local; row pair via xor 32)
    float pmax = s_[0];
    #pragma unroll
    for (int r = 1; r < 16; ++r) pmax = fmaxf(pmax, s_[r]);
    pmax = fmaxf(pmax, __shfl_xor(pmax, 32));
    if (!__all(pmax <= m + 8.0f)){
      float mn = fmaxf(m, pmax);
      float al = __expf(m - mn);
      m = mn; l *= al;
      #pragma unroll
      for (int dt = 0; dt < 4; ++dt) acc[dt] *= al;
    }
    float p[16]; float rs = 0.f;
    #pragma unroll
    for (int r = 0; r < 16; ++r){ p[r] = __expf(s_[r] - m); rs += p[r]; }
    rs += __shfl_xor(rs, 32);
    l += rs;
    // pack P^T into B-fragments
    unsigned A0 = (unsigned)f2bf(p[0])  | ((unsigned)f2bf(p[1])  << 16);
    unsigned A1 = (unsigned)f2bf(p[2])  | ((unsigned)f2bf(p[3])  << 16);
    unsigned A2 = (unsigned)f2bf(p[4])  | ((unsigned)f2bf(p[5])  << 16);
    unsigned A3 = (unsigned)f2bf(p[6])  | ((unsigned)f2bf(p[7])  << 16);
    unsigned A4 = (unsigned)f2bf(p[8])  | ((unsigned)f2bf(p[9])  << 16);
    unsigned A5 = (unsigned)f2bf(p[10]) | ((unsigned)f2bf(p[11]) << 16);
    unsigned A6 = (unsigned)f2bf(p[12]) | ((unsigned)f2bf(p[13]) << 16);
    unsigned A7 = (unsigned)f2bf(p[14]) | ((unsigned)f2bf(p[15]) << 16);
    unsigned S0 = __shfl_xor((int)A0, 32), S2 = __shfl_xor((int)A2, 32);
    unsigned S1 = __shfl_xor((int)A1, 32), S3 = __shfl_xor((int)A3, 32);
    unsigned S4 = __shfl_xor((int)A4, 32), S6 = __shfl_xor((int)A6, 32);
    unsigned S5 = __shfl_xor((int)A5, 32), S7 = __shfl_xor((int)A7, 32);
    union { unsigned u[4]; short8 s8; } P0, P1;
    P0.u[0] = hi ? S2 : A0;  P0.u[1] = hi ? S3 : A1;
    P0.u[2] = hi ? A2 : S0;  P0.u[3] = hi ? A3 : S1;
    P1.u[0] = hi ? S6 : A4;  P1.u[1] = hi ? S7 : A5;
    P1.u[2] = hi ? A6 : S4;  P1.u[3] = hi ? A7 : S5;
    // PV: own 128-dim quarter
    __builtin_amdgcn_s_setprio(1);
    #pragma unroll
    for (int dti = 0; dti < 4; ++dti){
      acc[dti] = __builtin_amdgcn_mfma_f32_32x32x16_bf16(vf[dti*2],     P0.s8, acc[dti], 0, 0, 0);
      acc[dti] = __builtin_amdgcn_mfma_f32_32x32x16_bf16(vf[dti*2 + 1], P1.s8, acc[dti], 0, 0, 0);
    }
    __builtin_amdgcn_s_setprio(0);
    __syncthreads();   // B2: sx reads done, K(kt+1) staged (vmcnt drain), kbuf swap safe
  }

  // ---- epilogue: normalize, transpose via LDS (alias over kbuf), coalesced store ----
  float il = 1.0f / l;
  #pragma unroll
  for (int dti = 0; dti < 4; ++dti){
    #pragma unroll
    for (int g = 0; g < 4; ++g){
      short4_ w;
      #pragma unroll
      for (int u = 0; u < 4; ++u) w[u] = (short)f2bf(acc[dti][g*4 + u] * il);
      *(short4_*)&ostage[ql*536 + wv*128 + dti*32 + g*8 + hi*4] = w;
    }
  }
  __syncthreads();
  {
    int row = tid >> 3, c8b = tid & 7;
    #pragma unroll
    for (int i = 0; i < 8; ++i){
      int c8 = c8b + i*8;
      *(short8*)(Ob + (size_t)(q0 + row)*DV + c8*8) = *(const short8*)&ostage[row*536 + c8*8];
    }
  }
}

// ---------------- k4: out equi-linear + residual ----------------
__global__ __launch_bounds__(256) void k4_out(
    const unsigned short* __restrict__ O, const unsigned short* __restrict__ wob,
    const float* __restrict__ x, float* __restrict__ out){
  extern __shared__ char smem[];
  unsigned short* oT = (unsigned short*)smem;
  float* fst = (float*)(smem + 69632);

  int tid = threadIdx.x, wv = tid >> 6, lane = tid & 63, lm = lane & 15, kg = lane >> 4;
  int blk = blockIdx.x;
  int b = blk >> 7, t0 = (blk & 127) << 4;

  for (int ch = tid; ch < 4096; ch += 256){
    int hh = ch >> 10, t = (ch >> 6) & 15, c8 = ch & 63;
    short8 v = *(const short8*)(O + ((size_t)(b*H_ + hh)*T_ + (t0 + t))*512 + c8*8);
    int c = c8 >> 1, j0 = (c8 & 1)*8;
    int ci = hh*32 + c;
    #pragma unroll
    for (int d = 0; d < 8; ++d)
      oT[((j0 + d)*16 + t)*136 + ci] = (unsigned short)v[d];
  }
  __syncthreads();

  #pragma unroll
  for (int bi = 0; bi < 4; ++bi){
    int j  = (int)((BL_PK >> ((wv*4 + bi)*4)) & 15);
    int g  = (int)((GRADE_PK >> (j*4)) & 15);
    bool e0 = (E0MASK >> j) & 1;
    int eb = (int)((E0B_PK >> (j*4)) & 15);
    int sj = (int)((SRC_PK >> (j*4)) & 15);
    #pragma unroll
    for (int nt = 0; nt < 2; ++nt){
      int o = nt*16 + lm;
      float4_ acc = {0.f, 0.f, 0.f, 0.f};
      #pragma unroll
      for (int ks = 0; ks < 4; ++ks){
        short8 a = *(const short8*)&oT[(j*16 + lm)*136 + ks*32 + kg*8];
        short8 bfr = *(const short8*)(wob + ((size_t)(g*32 + o))*128 + ks*32 + kg*8);
        acc = __builtin_amdgcn_mfma_f32_16x16x32_bf16(a, bfr, acc, 0, 0, 0);
      }
      if (e0){
        #pragma unroll
        for (int ks = 0; ks < 4; ++ks){
          short8 a = *(const short8*)&oT[(sj*16 + lm)*136 + ks*32 + kg*8];
          short8 bfr = *(const short8*)(wob + ((size_t)(eb*32 + o))*128 + ks*32 + kg*8);
          acc = __builtin_amdgcn_mfma_f32_16x16x32_bf16(a, bfr, acc, 0, 0, 0);
        }
      }
      #pragma unroll
      for (int r = 0; r < 4; ++r){
        int t = kg*4 + r;
        fst[t*512 + o*16 + j] = acc[r];
      }
    }
  }
  __syncthreads();
  const float* xb = x + ((size_t)(b*T_ + t0))*512;
  float* ob = out + ((size_t)(b*T_ + t0))*512;
  for (int ch = tid; ch < 2048; ch += 256){
    float4_ v  = *(const float4_*)(fst + (size_t)ch*4);
    float4_ xv = *(const float4_*)(xb + (size_t)ch*4);
    *(float4_*)(ob + (size_t)ch*4) = v + xv;
  }
}

// ---------------- launcher ----------------
extern "C" void kernel_launch(void* const* d_in, const int* in_sizes, int n_in,
                              void* d_out, int out_size, void* d_ws, size_t ws_size,
                              hipStream_t stream){
  const float* x       = (const float*)d_in[0];
  const float* lnw     = (const float*)d_in[1];
  const float* w_qkv   = (const float*)d_in[2];
  const float* w_out   = (const float*)d_in[3];
  const float* mix_ipa = (const float*)d_in[4];
  const float* mix_daa = (const float*)d_in[5];
  float* out = (float*)d_out;

  // qf 27,262,976 | kf 27,262,976 | vt 33,554,432 | O 33,554,432
  // wqb 221,184 | wob 73,728 | wI 512 | wD 512  => 121,930,752
  if (ws_size < 121930752u) return;

  char* ws = (char*)d_ws;
  unsigned short* qf  = (unsigned short*)(ws + 0);
  unsigned short* kf  = (unsigned short*)(ws + 27262976);
  unsigned short* vt  = (unsigned short*)(ws + 54525952);
  unsigned short* O   = (unsigned short*)(ws + 88080384);
  unsigned short* wqb = (unsigned short*)(ws + 121634816);
  unsigned short* wob = (unsigned short*)(ws + 121856000);
  float* wI = (float*)(ws + 121929728);
  float* wD = (float*)(ws + 121930240);

  k0_prep<<<432, 256, 0, stream>>>(w_qkv, w_out, lnw, mix_ipa, mix_daa, wqb, wob, wI, wD);
  k1_qkv<<<512, 256, 111168, stream>>>(x, wqb, wI, wD, qf, kf, vt);
  k3_attn<<<1024, 256, 71680, stream>>>(qf, kf, vt, O);
  k4_out<<<512, 256, 102400, stream>>>(O, wob, x, out);
}